// Round 6
// baseline (434.353 us; speedup 1.0000x reference)
//
#include <hip/hip_runtime.h>

// FocalLoss (RetinaNet) on MI355X — fused 2-kernel design, no memset, no atomics.
// R5: negative-anchor fast path in the cls sweep; wave-per-image finalize.
//
// dur_us model (R4 evidence): ~365 us is harness reset fills (d_ws 1.2GB poison
// at ~183 us + d_in restore) included in the timed window; our kernels are the
// remaining ~70 us. Controllable floor ~53 us (307 MB cls sweep at 6.3 TB/s).

#define CHUNK 256

template <int KV>   // K/4 as compile-time constant (magic-mul div/mod)
__global__ __launch_bounds__(256) void fused_kernel(
    const float* __restrict__ cls,       // [B,A,K]
    const float* __restrict__ regr,      // [B,A,4]
    const float* __restrict__ anchors,   // [A,4]
    const float* __restrict__ ann_g,     // [B,M,5]
    float* __restrict__ pcls,            // [B,nblk]
    float* __restrict__ preg,            // [B,nblk]
    float* __restrict__ ppos,            // [B,nblk]
    int A, int M)
{
    const int b   = blockIdx.y;
    const int blk = blockIdx.x;
    const int a0  = blk * CHUNK;
    const int tid = threadIdx.x;

    __shared__ float ann[512];          // M*5 floats (M<=102)
    __shared__ int   smeta[CHUNK];
    const int nl = M * 5;
    for (int i = tid; i < nl; i += 256) ann[i] = ann_g[b * nl + i];
    __syncthreads();

    // ---- Phase 1: assignment for anchor a0+tid ----
    float regl = 0.0f, posf = 0.0f;
    int mv = -2;                        // pad anchors: treated as "ignore"
    const int a = a0 + tid;
    if (a < A) {
        const float4 ab = *reinterpret_cast<const float4*>(anchors + (size_t)a * 4);
        const float aw = ab.z - ab.x, ah = ab.w - ab.y;
        const float areaA = aw * ah;

        float best = -3.0e38f;
        int arg = 0;
        for (int m = 0; m < M; ++m) {
            const float bx1 = ann[m * 5 + 0], by1 = ann[m * 5 + 1];
            const float bx2 = ann[m * 5 + 2], by2 = ann[m * 5 + 3];
            const float lb  = ann[m * 5 + 4];
            float iw = fmaxf(fminf(ab.z, bx2) - fmaxf(ab.x, bx1), 0.0f);
            float ih = fmaxf(fminf(ab.w, by2) - fmaxf(ab.y, by1), 0.0f);
            float inter = iw * ih;
            float ua = fmaxf(areaA + (bx2 - bx1) * (by2 - by1) - inter, 1e-8f);
            float iou = inter / ua;
            iou = (lb != -1.0f) ? iou : -1.0f;        // mask padded GTs
            if (iou > best) { best = iou; arg = m; }  // strict > == first-occurrence argmax
        }

        if (best >= 0.5f) {
            mv = (int)ann[arg * 5 + 4];               // positive: class label
            posf = 1.0f;
            const float4 rg = *reinterpret_cast<const float4*>(
                regr + ((size_t)b * A + a) * 4);
            const float gx1 = ann[arg * 5 + 0], gy1 = ann[arg * 5 + 1];
            const float gx2 = ann[arg * 5 + 2], gy2 = ann[arg * 5 + 3];
            const float acx = ab.x + 0.5f * aw, acy = ab.y + 0.5f * ah;
            const float gwr = gx2 - gx1, ghr = gy2 - gy1;
            const float gcx = gx1 + 0.5f * gwr, gcy = gy1 + 0.5f * ghr;
            const float gw = fmaxf(gwr, 1.0f), gh = fmaxf(ghr, 1.0f);
            const float t0 = ((gcx - acx) / aw) / 0.1f;
            const float t1 = ((gcy - acy) / ah) / 0.1f;
            const float t2 = logf(gw / aw) / 0.2f;
            const float t3 = logf(gh / ah) / 0.2f;
            const float d0 = fabsf(t0 - rg.x), d1 = fabsf(t1 - rg.y);
            const float d2 = fabsf(t2 - rg.z), d3 = fabsf(t3 - rg.w);
            const float th = 1.0f / 9.0f, c = 0.5f / 9.0f;
            regl  = (d0 <= th) ? 4.5f * d0 * d0 : d0 - c;
            regl += (d1 <= th) ? 4.5f * d1 * d1 : d1 - c;
            regl += (d2 <= th) ? 4.5f * d2 * d2 : d2 - c;
            regl += (d3 <= th) ? 4.5f * d3 * d3 : d3 - c;
        } else if (best < 0.4f) {
            mv = -1;                                  // negative: t = 0 row
        }                                             // else ignore band -> -2
    }
    smeta[tid] = mv;
    __syncthreads();

    // ---- Phase 2: focal loss over this chunk's classification slab ----
    const int span = min(CHUNK, A - a0);
    const int nv = span * KV;
    const float4* __restrict__ base =
        reinterpret_cast<const float4*>(cls + ((size_t)b * A + a0) * (KV * 4));

    float acc = 0.0f;
    for (int t = tid; t < nv; t += 256) {
        const float4 c4 = base[t];
        const int la    = t / KV;          // local anchor (magic-mul)
        const int m2 = smeta[la];
        const float cv[4] = {c4.x, c4.y, c4.z, c4.w};
        if (m2 == -1) {
            // negative anchor (dominant, wave-quasi-uniform): t = 0 for all K
            #pragma unroll
            for (int j = 0; j < 4; ++j) {
                const float cc = fminf(fmaxf(cv[j], 1e-4f), 0.9999f);
                acc += 0.75f * cc * cc * (-__logf(1.0f - cc));
            }
        } else if (m2 >= 0) {
            // positive anchor: one-hot target row
            const int kbase = (t % KV) * 4;
            #pragma unroll
            for (int j = 0; j < 4; ++j) {
                const float cc = fminf(fmaxf(cv[j], 1e-4f), 0.9999f);
                const bool t1 = (m2 == kbase + j);
                const float x = t1 ? cc : (1.0f - cc);
                const float w = t1 ? 0.25f * (1.0f - cc) * (1.0f - cc)
                                   : 0.75f * cc * cc;
                acc += w * (-__logf(x));
            }
        }
        // m2 == -2 (ignore band / pad): contributes nothing
    }

    // ---- block reduction of acc / regl / posf ----
    #pragma unroll
    for (int off = 32; off > 0; off >>= 1) {
        acc  += __shfl_down(acc,  off, 64);
        regl += __shfl_down(regl, off, 64);
        posf += __shfl_down(posf, off, 64);
    }
    __shared__ float wred[12];
    const int wave = tid >> 6, lane = tid & 63;
    if (lane == 0) { wred[wave] = acc; wred[4 + wave] = regl; wred[8 + wave] = posf; }
    __syncthreads();
    if (tid == 0) {
        const size_t o = (size_t)b * gridDim.x + blk;
        pcls[o] = wred[0] + wred[1] + wred[2] + wred[3];
        preg[o] = wred[4] + wred[5] + wred[6] + wred[7];
        ppos[o] = wred[8] + wred[9] + wred[10] + wred[11];
    }
}

// runtime-KV fallback (identical structure)
__global__ __launch_bounds__(256) void fused_generic(
    const float* __restrict__ cls, const float* __restrict__ regr,
    const float* __restrict__ anchors, const float* __restrict__ ann_g,
    float* __restrict__ pcls, float* __restrict__ preg, float* __restrict__ ppos,
    int A, int M, int KV)
{
    const int b   = blockIdx.y;
    const int blk = blockIdx.x;
    const int a0  = blk * CHUNK;
    const int tid = threadIdx.x;

    __shared__ float ann[512];
    __shared__ int   smeta[CHUNK];
    const int nl = M * 5;
    for (int i = tid; i < nl; i += 256) ann[i] = ann_g[b * nl + i];
    __syncthreads();

    float regl = 0.0f, posf = 0.0f;
    int mv = -2;
    const int a = a0 + tid;
    if (a < A) {
        const float4 ab = *reinterpret_cast<const float4*>(anchors + (size_t)a * 4);
        const float aw = ab.z - ab.x, ah = ab.w - ab.y;
        const float areaA = aw * ah;
        float best = -3.0e38f; int arg = 0;
        for (int m = 0; m < M; ++m) {
            const float bx1 = ann[m*5+0], by1 = ann[m*5+1];
            const float bx2 = ann[m*5+2], by2 = ann[m*5+3];
            const float lb  = ann[m*5+4];
            float iw = fmaxf(fminf(ab.z, bx2) - fmaxf(ab.x, bx1), 0.0f);
            float ih = fmaxf(fminf(ab.w, by2) - fmaxf(ab.y, by1), 0.0f);
            float inter = iw * ih;
            float ua = fmaxf(areaA + (bx2-bx1)*(by2-by1) - inter, 1e-8f);
            float iou = inter / ua;
            iou = (lb != -1.0f) ? iou : -1.0f;
            if (iou > best) { best = iou; arg = m; }
        }
        if (best >= 0.5f) {
            mv = (int)ann[arg*5+4]; posf = 1.0f;
            const float4 rg = *reinterpret_cast<const float4*>(regr + ((size_t)b*A + a)*4);
            const float gx1 = ann[arg*5+0], gy1 = ann[arg*5+1];
            const float gx2 = ann[arg*5+2], gy2 = ann[arg*5+3];
            const float acx = ab.x + 0.5f*aw, acy = ab.y + 0.5f*ah;
            const float gwr = gx2-gx1, ghr = gy2-gy1;
            const float gcx = gx1 + 0.5f*gwr, gcy = gy1 + 0.5f*ghr;
            const float gw = fmaxf(gwr, 1.0f), gh = fmaxf(ghr, 1.0f);
            const float t0 = ((gcx-acx)/aw)/0.1f, t1 = ((gcy-acy)/ah)/0.1f;
            const float t2 = logf(gw/aw)/0.2f,    t3 = logf(gh/ah)/0.2f;
            const float d0 = fabsf(t0-rg.x), d1 = fabsf(t1-rg.y);
            const float d2 = fabsf(t2-rg.z), d3 = fabsf(t3-rg.w);
            const float th = 1.0f/9.0f, c = 0.5f/9.0f;
            regl  = (d0<=th)?4.5f*d0*d0:d0-c;  regl += (d1<=th)?4.5f*d1*d1:d1-c;
            regl += (d2<=th)?4.5f*d2*d2:d2-c;  regl += (d3<=th)?4.5f*d3*d3:d3-c;
        } else if (best < 0.4f) { mv = -1; }
    }
    smeta[tid] = mv;
    __syncthreads();

    const int span = min(CHUNK, A - a0);
    const int nv = span * KV;
    const float4* __restrict__ base =
        reinterpret_cast<const float4*>(cls + ((size_t)b*A + a0) * (KV*4));
    float acc = 0.0f;
    for (int t = tid; t < nv; t += 256) {
        const float4 c4 = base[t];
        const int la = t / KV;
        const int m2 = smeta[la];
        const float cv[4] = {c4.x, c4.y, c4.z, c4.w};
        if (m2 == -1) {
            #pragma unroll
            for (int j = 0; j < 4; ++j) {
                const float cc = fminf(fmaxf(cv[j], 1e-4f), 0.9999f);
                acc += 0.75f * cc * cc * (-__logf(1.0f - cc));
            }
        } else if (m2 >= 0) {
            const int kbase = (t % KV) * 4;
            #pragma unroll
            for (int j = 0; j < 4; ++j) {
                const float cc = fminf(fmaxf(cv[j], 1e-4f), 0.9999f);
                const bool t1 = (m2 == kbase + j);
                const float x = t1 ? cc : (1.0f - cc);
                const float w = t1 ? 0.25f*(1.0f-cc)*(1.0f-cc) : 0.75f*cc*cc;
                acc += w * (-__logf(x));
            }
        }
    }

    #pragma unroll
    for (int off = 32; off > 0; off >>= 1) {
        acc  += __shfl_down(acc,  off, 64);
        regl += __shfl_down(regl, off, 64);
        posf += __shfl_down(posf, off, 64);
    }
    __shared__ float wred[12];
    const int wave = tid >> 6, lane = tid & 63;
    if (lane == 0) { wred[wave] = acc; wred[4+wave] = regl; wred[8+wave] = posf; }
    __syncthreads();
    if (tid == 0) {
        const size_t o = (size_t)b * gridDim.x + blk;
        pcls[o] = wred[0]+wred[1]+wred[2]+wred[3];
        preg[o] = wred[4]+wred[5]+wred[6]+wred[7];
        ppos[o] = wred[8]+wred[9]+wred[10]+wred[11];
    }
}

// One wave per image; single __syncthreads; has_valid via per-lane load + __any.
__global__ __launch_bounds__(512) void finalize_kernel(
    const float* __restrict__ ann_g,    // [B,M,5]
    const float* __restrict__ pcls,
    const float* __restrict__ preg,
    const float* __restrict__ ppos,
    float* __restrict__ out,
    int B, int M, int nblk)
{
    const int tid  = threadIdx.x;
    const int wave = tid >> 6;
    const int lane = tid & 63;
    const int nw   = blockDim.x >> 6;   // 8 waves

    __shared__ float sct[64], srt[64];  // per-image results (B <= 64)

    for (int b = wave; b < B; b += nw) {
        float c = 0.0f, r = 0.0f, p = 0.0f;
        for (int i = lane; i < nblk; i += 64) {
            const size_t o = (size_t)b * nblk + i;
            c += pcls[o]; r += preg[o]; p += ppos[o];
        }
        #pragma unroll
        for (int off = 32; off > 0; off >>= 1) {
            c += __shfl_down(c, off, 64);
            r += __shfl_down(r, off, 64);
            p += __shfl_down(p, off, 64);
        }
        bool hvl = false;
        for (int m = lane; m < M; m += 64)
            hvl = hvl || (ann_g[((size_t)b * M + m) * 5 + 4] != -1.0f);
        const bool hv = __any(hvl);
        if (lane == 0) {
            sct[b] = hv ? c / fmaxf(p, 1.0f) : 0.0f;
            srt[b] = (p > 0.0f) ? r / fmaxf(p * 4.0f, 1.0f) : 0.0f;
        }
    }
    __syncthreads();
    if (tid == 0) {
        float cm = 0.0f, rm = 0.0f;
        for (int b = 0; b < B; ++b) { cm += sct[b]; rm += srt[b]; }
        out[0] = cm / (float)B;
        out[1] = rm / (float)B;
    }
}

extern "C" void kernel_launch(void* const* d_in, const int* in_sizes, int n_in,
                              void* d_out, int out_size, void* d_ws, size_t ws_size,
                              hipStream_t stream) {
    const float* cls = (const float*)d_in[0];   // [B,A,K]
    const float* reg = (const float*)d_in[1];   // [B,A,4]
    const float* anc = (const float*)d_in[2];   // [1,A,4]
    const float* ann = (const float*)d_in[3];   // [B,M,5]

    const int A = in_sizes[2] / 4;
    const int B = in_sizes[1] / (A * 4);
    const int M = in_sizes[3] / (B * 5);
    const int K = in_sizes[0] / (B * A);
    const int nblk = (A + CHUNK - 1) / CHUNK;

    float* out = (float*)d_out;
    // workspace: three [B,nblk] partial arrays; every slot written by kernel 1.
    float* pcls = (float*)d_ws;
    float* preg = pcls + (size_t)B * nblk;
    float* ppos = preg + (size_t)B * nblk;

    dim3 grid(nblk, B);
    if (K == 80) {
        fused_kernel<20><<<grid, 256, 0, stream>>>(cls, reg, anc, ann,
                                                   pcls, preg, ppos, A, M);
    } else {
        fused_generic<<<grid, 256, 0, stream>>>(cls, reg, anc, ann,
                                                pcls, preg, ppos, A, M, K / 4);
    }
    finalize_kernel<<<1, 512, 0, stream>>>(ann, pcls, preg, ppos, out, B, M, nblk);
}